// Round 13
// baseline (365.381 us; speedup 1.0000x reference)
//
#include <hip/hip_runtime.h>
#include <math.h>

#define VERY_NEG  -100000000000.0f
#define VERY_SMALLF 1e-10f

constexpr int B  = 8;
constexpr int E  = 2000;
constexpr int FC = 12000;
constexpr int Q  = 20;
constexpr int WD = 300;
constexpr int D  = 100;
constexpr int NW = 40000;
constexpr int NE = 100000;
constexpr int G4 = 4 * D;   // 400
constexpr int NREL = 301;
constexpr int NF = B * FC;  // 96000
constexpr int NR_ = B * E;  // 16000 rows
constexpr int NRP = 16384;

__device__ __forceinline__ float sigmoidf_(float x) { return 1.0f / (1.0f + expf(-x)); }

// ================= GEMM micro-kernels =================
// tile16: 4 rows x 4 cols per thread (32-row tiles, 256 thr)
__device__ __forceinline__ void tile16(const float* __restrict__ As_, const float* __restrict__ Bs_,
                                       int rg, int cgc, float acc[4][4]) {
#pragma unroll 5
    for (int k4 = 0; k4 < 25; ++k4) {
        float a_[4][4], b_[4][4];
#pragma unroll
        for (int i = 0; i < 4; ++i) {
            float4 v = *(const float4*)&As_[(rg * 4 + i) * 104 + k4 * 4];
            a_[i][0] = v.x; a_[i][1] = v.y; a_[i][2] = v.z; a_[i][3] = v.w;
        }
#pragma unroll
        for (int kk = 0; kk < 4; ++kk) {
            float4 v = *(const float4*)&Bs_[(k4 * 4 + kk) * 100 + cgc * 4];
            b_[kk][0] = v.x; b_[kk][1] = v.y; b_[kk][2] = v.z; b_[kk][3] = v.w;
        }
#pragma unroll
        for (int kk = 0; kk < 4; ++kk)
#pragma unroll
            for (int i = 0; i < 4; ++i)
#pragma unroll
                for (int j = 0; j < 4; ++j)
                    acc[i][j] += a_[i][kk] * b_[kk][j];
    }
}

// tile8: 2 rows x 4 cols per thread (16-row tiles, 256 thr)
__device__ __forceinline__ void tile8(const float* __restrict__ As_, const float* __restrict__ Bs_,
                                      int rg, int cgc, float acc[2][4]) {
#pragma unroll 5
    for (int k4 = 0; k4 < 25; ++k4) {
        float a_[2][4], b_[4][4];
#pragma unroll
        for (int i = 0; i < 2; ++i) {
            float4 v = *(const float4*)&As_[(rg * 2 + i) * 104 + k4 * 4];
            a_[i][0] = v.x; a_[i][1] = v.y; a_[i][2] = v.z; a_[i][3] = v.w;
        }
#pragma unroll
        for (int kk = 0; kk < 4; ++kk) {
            float4 v = *(const float4*)&Bs_[(k4 * 4 + kk) * 100 + cgc * 4];
            b_[kk][0] = v.x; b_[kk][1] = v.y; b_[kk][2] = v.z; b_[kk][3] = v.w;
        }
#pragma unroll
        for (int kk = 0; kk < 4; ++kk)
#pragma unroll
            for (int i = 0; i < 2; ++i)
#pragma unroll
                for (int j = 0; j < 4; ++j)
                    acc[i][j] += a_[i][kk] * b_[kk][j];
    }
}

__device__ __forceinline__ void stage_B100(const float* __restrict__ Wt, int ldW, int col0, int k0,
                                           float* __restrict__ Bs_) {
    for (int i = threadIdx.x; i < 2500; i += 256) {
        int k = i / 25, d2 = i - k * 25;
        *(float4*)&Bs_[k * 100 + d2 * 4] = *(const float4*)&Wt[(size_t)(k0 + k) * ldW + col0 + d2 * 4];
    }
}

__device__ void gemm_tile_g(const float* __restrict__ A, int K,
                            const int* __restrict__ rix, int nrows,
                            const float* __restrict__ Wt, int ldW, int col0,
                            const float* __restrict__ bias,
                            float* __restrict__ C,
                            int base, float* As_, float* Bs_) {
    int tid = threadIdx.x;
    int cg_ = tid & 31, rg = tid >> 5, cgc = cg_ < 25 ? cg_ : 24;
    float acc[4][4] = {{0.f}};
    for (int k0 = 0; k0 < K; k0 += 100) {
        __syncthreads();
        for (int i = tid; i < 800; i += 256) {
            int r = i / 25, c = i - r * 25;
            int rr = base + r; if (rr >= nrows) rr = nrows - 1;
            int gr = rix ? rix[rr] : rr;
            *(float4*)&As_[r * 104 + c * 4] = *(const float4*)&A[(size_t)gr * K + k0 + c * 4];
        }
        stage_B100(Wt, ldW, col0, k0, Bs_);
        __syncthreads();
        tile16(As_, Bs_, rg, cgc, acc);
    }
    if (cg_ < 25) {
        float4 bb = *(const float4*)&bias[col0 + cg_ * 4];
#pragma unroll
        for (int i = 0; i < 4; ++i) {
            int r = base + rg * 4 + i;
            if (r < nrows) {
                float4 o;
                o.x = acc[i][0] + bb.x; o.y = acc[i][1] + bb.y;
                o.z = acc[i][2] + bb.z; o.w = acc[i][3] + bb.w;
                *(float4*)&C[(size_t)r * ldW + col0 + cg_ * 4] = o;
            }
        }
    }
}

__device__ void gemm_tile_512(const float* __restrict__ A, int K,
                              const int* __restrict__ rix, int nrows,
                              const float* __restrict__ Wt, int ldW, int col0,
                              const float* __restrict__ bias,
                              float* __restrict__ C,
                              int base, float* As_, float* Bs_) {
    int tid = threadIdx.x;
    int cg_ = tid & 31, rg = (tid >> 5) & 7, cgc = cg_ < 25 ? cg_ : 24;
    bool on = tid < 256;
    float acc[4][4] = {{0.f}};
    for (int k0 = 0; k0 < K; k0 += 100) {
        __syncthreads();
        for (int i = tid; i < 800; i += 512) {
            int r = i / 25, c = i - r * 25;
            int rr = base + r; if (rr >= nrows) rr = nrows - 1;
            int gr = rix ? rix[rr] : rr;
            *(float4*)&As_[r * 104 + c * 4] = *(const float4*)&A[(size_t)gr * K + k0 + c * 4];
        }
        for (int i = tid; i < 2500; i += 512) {
            int k = i / 25, d2 = i - k * 25;
            *(float4*)&Bs_[k * 100 + d2 * 4] = *(const float4*)&Wt[(size_t)(k0 + k) * ldW + col0 + d2 * 4];
        }
        __syncthreads();
        if (on) tile16(As_, Bs_, rg, cgc, acc);
    }
    if (on && cg_ < 25) {
        float4 bb = *(const float4*)&bias[col0 + cg_ * 4];
#pragma unroll
        for (int i = 0; i < 4; ++i) {
            int r = base + rg * 4 + i;
            if (r < nrows) {
                float4 o;
                o.x = acc[i][0] + bb.x; o.y = acc[i][1] + bb.y;
                o.z = acc[i][2] + bb.z; o.w = acc[i][3] + bb.w;
                *(float4*)&C[(size_t)r * ldW + col0 + cg_ * 4] = o;
            }
        }
    }
}

// ================= prep0: transposes + fills + hist =================
struct P0 {
    const float *ent_W, *rel_W, *Wih, *Whh, *head_W, *self_W, *tail_W, *e2e_W, *bih, *bhh, *q2e_adj;
    float *entWt, *relWt, *WihT, *WhhT, *headWt, *selfWt, *tailWt, *e2eWt, *bihh, *pr, *e2f_sm;
    const int *f2e, *kb_rel; int *cnt, *present;
};

__device__ void tr_tile(const float* __restrict__ in, float* __restrict__ out, int M, int K,
                        int kx, int my, float tb[32][33]) {
    int x = threadIdx.x & 31, y = threadIdx.x >> 5;
    int k0 = kx * 32, m0 = my * 32;
    for (int yy = y; yy < 32; yy += 8) {
        int m = m0 + yy, k = k0 + x;
        if (m < M && k < K) tb[yy][x] = in[(size_t)m * K + k];
    }
    __syncthreads();
    for (int yy = y; yy < 32; yy += 8) {
        int k = k0 + yy, m = m0 + x;
        if (m < M && k < K) out[(size_t)k * M + m] = tb[x][yy];
    }
}

__global__ __launch_bounds__(256) void k_prep0(P0 p) {
    __shared__ float tb[32][33];
    int j = blockIdx.x, tid = threadIdx.x;
    if (j < 40)       { tr_tile(p.ent_W, p.entWt, 100, 300, j % 10, j / 10, tb); }
    else if (j < 116) { j -= 40;  tr_tile(p.rel_W, p.relWt, 100, 600, j % 19, j / 19, tb); }
    else if (j < 246) { j -= 116; tr_tile(p.Wih, p.WihT, 400, 300, j % 10, j / 10, tb); }
    else if (j < 298) { j -= 246; tr_tile(p.Whh, p.WhhT, 400, 100, j % 4, j / 4, tb); }
    else if (j < 346) { j -= 298; int z = j / 16, t = j % 16; tr_tile(p.head_W + z * 10000, p.headWt + z * 10000, 100, 100, t % 4, t / 4, tb); }
    else if (j < 394) { j -= 346; int z = j / 16, t = j % 16; tr_tile(p.self_W + z * 10000, p.selfWt + z * 10000, 100, 100, t % 4, t / 4, tb); }
    else if (j < 442) { j -= 394; int z = j / 16, t = j % 16; tr_tile(p.tail_W + z * 10000, p.tailWt + z * 10000, 100, 100, t % 4, t / 4, tb); }
    else if (j < 562) { j -= 442; int z = j / 40, t = j % 40; tr_tile(p.e2e_W + z * 30000, p.e2eWt + z * 30000, 100, 300, t % 10, t / 10, tb); }
    else if (j < 564) { int idx = (j - 562) * 256 + tid; if (idx < G4) p.bihh[idx] = p.bih[idx] + p.bhh[idx]; }
    else if (j < 580) { int idx = (j - 564) * 256 + tid; if (idx < 4000) ((float4*)p.pr)[idx] = ((const float4*)p.q2e_adj)[idx]; }
    else if (j < 596) { int idx = (j - 580) * 256 + tid; if (idx < 4000) ((float4*)p.e2f_sm)[idx] = make_float4(0.f, 0.f, 0.f, 0.f); }
    else {
        int fid = (j - 596) * 256 + tid;   // [0, 96000) exact
        int b = fid / FC;
        atomicAdd(&p.cnt[b * E + p.f2e[fid]], 1);
        p.present[b * NREL + p.kb_rel[fid]] = 1;
    }
}

// ================= front1: scan + xW GEMM + rel_proj GEMM + lee_dual (16-row) =================
struct F1P {
    const int *cnt; int *off, *cursor; float *cnt_f;
    const float *word_emb; const int *qtext; const float *WihT, *bihh; float *xW;
    const float *rel_emb, *relWt, *rel_b; float *rel_proj;
    const float *entity_emb; const int *local_entity;
    const float *entWt, *ent_b, *headWt0, *head_b0, *selfWt0, *self_b0;
    float *lee, *head, *lee_self;
};

__device__ void scan_block(const int* __restrict__ cnt, int* __restrict__ off,
                           int* __restrict__ cursor, float* __restrict__ cnt_f, int* part) {
    int t = threadIdx.x;
    int s = 0;
    const int4* c4 = (const int4*)(cnt + t * 64);
#pragma unroll 4
    for (int i = 0; i < 16; ++i) { int4 v = c4[i]; s += v.x + v.y + v.z + v.w; }
    part[t] = s;
    __syncthreads();
    for (int d = 1; d < 256; d <<= 1) {
        int add = (t >= d) ? part[t - d] : 0;
        __syncthreads();
        part[t] += add;
        __syncthreads();
    }
    int run = part[t] - s;
    for (int i = 0; i < 64; ++i) {
        int idx = t * 64 + i;
        if (idx < NR_) {
            off[idx] = run; cursor[idx] = run; cnt_f[idx] = (float)cnt[idx];
            run += cnt[idx];
        }
    }
    if (t == 255) off[NR_] = part[255];
}

__device__ void lee_dual_tile16(int base, const F1P& p, float* As_, float* Bs_) {
    int tid = threadIdx.x;
    int cg_ = tid & 31, rg = tid >> 5, cgc = cg_ < 25 ? cg_ : 24;
    float acc[2][4] = {{0.f}};
    for (int k0 = 0; k0 < 300; k0 += 100) {
        __syncthreads();
        for (int i = tid; i < 400; i += 256) {
            int r = i / 25, c = i - r * 25;
            int gr = p.local_entity[base + r];
            *(float4*)&As_[r * 104 + c * 4] = *(const float4*)&p.entity_emb[(size_t)gr * 300 + k0 + c * 4];
        }
        stage_B100(p.entWt, 100, 0, k0, Bs_);
        __syncthreads();
        tile8(As_, Bs_, rg, cgc, acc);
    }
    __syncthreads();
    if (cg_ < 25) {
        float4 bb = *(const float4*)&p.ent_b[cg_ * 4];
#pragma unroll
        for (int i = 0; i < 2; ++i) {
            int r = base + rg * 2 + i;
            float4 o;
            o.x = acc[i][0] + bb.x; o.y = acc[i][1] + bb.y;
            o.z = acc[i][2] + bb.z; o.w = acc[i][3] + bb.w;
            *(float4*)&p.lee[(size_t)r * 100 + cg_ * 4] = o;
            *(float4*)&As_[(rg * 2 + i) * 104 + cg_ * 4] = o;
        }
    }
    stage_B100(p.headWt0, 100, 0, 0, Bs_);
    __syncthreads();
    float acc2[2][4] = {{0.f}};
    tile8(As_, Bs_, rg, cgc, acc2);
    if (cg_ < 25) {
        float4 bb = *(const float4*)&p.head_b0[cg_ * 4];
#pragma unroll
        for (int i = 0; i < 2; ++i) {
            int r = base + rg * 2 + i;
            float4 o;
            o.x = acc2[i][0] + bb.x; o.y = acc2[i][1] + bb.y;
            o.z = acc2[i][2] + bb.z; o.w = acc2[i][3] + bb.w;
            *(float4*)&p.head[(size_t)r * 100 + cg_ * 4] = o;
        }
    }
    __syncthreads();
    stage_B100(p.selfWt0, 100, 0, 0, Bs_);
    __syncthreads();
    float acc3[2][4] = {{0.f}};
    tile8(As_, Bs_, rg, cgc, acc3);
    if (cg_ < 25) {
        float4 bb = *(const float4*)&p.self_b0[cg_ * 4];
#pragma unroll
        for (int i = 0; i < 2; ++i) {
            int r = base + rg * 2 + i;
            float4 o;
            o.x = acc3[i][0] + bb.x; o.y = acc3[i][1] + bb.y;
            o.z = acc3[i][2] + bb.z; o.w = acc3[i][3] + bb.w;
            *(float4*)&p.lee_self[(size_t)r * 100 + cg_ * 4] = o;
        }
    }
}

__global__ __launch_bounds__(256) void k_front1(F1P p) {
    __shared__ float smem[13328];
    int j = blockIdx.x;
    if (j == 0) {
        scan_block(p.cnt, p.off, p.cursor, p.cnt_f, (int*)smem);
    } else if (j <= 20) {
        j -= 1;
        gemm_tile_g(p.word_emb, WD, p.qtext, B * Q, p.WihT, G4, (j / 5) * 100, p.bihh,
                    p.xW, (j % 5) * 32, smem, smem + 3328);
    } else if (j <= 30) {
        j -= 21;
        gemm_tile_g(p.rel_emb, 2 * WD, nullptr, NREL, p.relWt, D, 0, p.rel_b,
                    p.rel_proj, j * 32, smem, smem + 3328);
    } else {
        lee_dual_tile16((j - 31) * 16, p, smem, smem + 1664);
    }
}

// ================= front2: LSTM+q2e+wfall fused + self_proj =================
struct F2P {
    const float *xW, *WhhT, *q2e_W, *q2e_b; float *q2e_vec;
    const int *qtext, *present;
    const float *rel_proj; float *Wt_rel;
    const float *selfWt, *self_b; float *self_proj;
};

__device__ void lstm_wfall_block(int b, const F2P& p, float* smem) {
    float* h    = smem;
    float* c    = smem + 128;
    float* gate = smem + 256;
    float* qh_s = smem + 704;
    float* msk  = smem + 2704;
    float* red  = smem + 2752;
    int t = threadIdx.x;         // 512 threads
    float w[100];
    if (t < G4) {
#pragma unroll
        for (int j = 0; j < 100; ++j) w[j] = p.WhhT[j * G4 + t];
    }
    if (t < D) { h[t] = 0.f; c[t] = 0.f; }
    if (t < Q) msk[t] = (p.qtext[b * Q + t] != NW) ? 1.f : 0.f;
    __syncthreads();
    for (int step = 0; step < Q; ++step) {
        if (t < G4) {
            float a0 = 0.f, a1 = 0.f, a2 = 0.f, a3 = 0.f;
#pragma unroll
            for (int k4 = 0; k4 < 25; ++k4) {
                float4 hv = *(const float4*)&h[k4 * 4];
                a0 += hv.x * w[k4 * 4 + 0];
                a1 += hv.y * w[k4 * 4 + 1];
                a2 += hv.z * w[k4 * 4 + 2];
                a3 += hv.w * w[k4 * 4 + 3];
            }
            gate[t] = p.xW[(b * Q + step) * G4 + t] + ((a0 + a1) + (a2 + a3));
        }
        __syncthreads();
        if (t < D) {
            float ig = sigmoidf_(gate[t]);
            float fg = sigmoidf_(gate[D + t]);
            float gg = tanhf(gate[2 * D + t]);
            float og = sigmoidf_(gate[3 * D + t]);
            float cn = fg * c[t] + ig * gg;
            c[t] = cn;
            float hn = og * tanhf(cn);
            h[t] = hn;
            qh_s[step * D + t] = hn;
        }
        __syncthreads();
    }
    if (t < 3 * D) {
        int l = t / D, d = t - l * D;
        float acc = p.q2e_b[l * D + d];
        const float* W = p.q2e_W + (size_t)(l * D + d) * D;
        for (int k = 0; k < D; ++k) acc += h[k] * W[k];
        p.q2e_vec[(l * B + b) * D + d] = acc;
    }
    float wf = 0.f;
    bool active = t < NREL;
    if (active) {
        const float* lfe = p.rel_proj + t * D;
        float s[Q];
#pragma unroll
        for (int q = 0; q < Q; ++q) s[q] = 0.f;
        for (int k = 0; k < D; ++k) {
            float lv = lfe[k];
#pragma unroll
            for (int q = 0; q < Q; ++q) s[q] += qh_s[q * D + k] * lv;
        }
        float m = -INFINITY;
        float sv[Q];
#pragma unroll
        for (int q = 0; q < Q; ++q) {
            s[q] *= 0.1f;
            sv[q] = s[q] + (1.f - msk[q]) * VERY_NEG;
            m = fmaxf(m, sv[q]);
        }
        float sum = 0.f;
        float ex[Q];
#pragma unroll
        for (int q = 0; q < Q; ++q) { ex[q] = expf(sv[q] - m); sum += ex[q]; }
#pragma unroll
        for (int q = 0; q < Q; ++q) wf += (ex[q] / sum) * s[q];
    }
    red[t] = (active && p.present[b * NREL + t]) ? wf : -INFINITY;
    __syncthreads();
    for (int st = 256; st > 0; st >>= 1) {
        if (t < st) red[t] = fmaxf(red[t], red[t + st]);
        __syncthreads();
    }
    if (active) p.Wt_rel[b * NREL + t] = expf(wf - red[0]);
}

__global__ __launch_bounds__(512) void k_front2(F2P p) {
    __shared__ float smem[13328];
    int j = blockIdx.x;
    if (j < 8) {
        lstm_wfall_block(j, p, smem);
    } else {
        j -= 8;
        int z = j / 10, t = j % 10;
        gemm_tile_512(p.rel_proj, D, nullptr, NREL, p.selfWt + z * 10000, D, 0, p.self_b + z * 100,
                      p.self_proj + (size_t)z * NREL * D, t * 32, smem, smem + 3328);
    }
}

// ================= sc_ef =================
__global__ void k_scef(const int* __restrict__ f2e, const int* __restrict__ e2f,
                       const int* __restrict__ kb_rel, const float* __restrict__ Wt_rel,
                       int* __restrict__ cursor, int* __restrict__ sorted,
                       float* __restrict__ W_tilde, float* __restrict__ e2f_sm) {
    int fid = blockIdx.x * 256 + threadIdx.x;
    int b = fid / FC;
    int pos = atomicAdd(&cursor[b * E + f2e[fid]], 1);
    sorted[pos] = fid;
    float wt = Wt_rel[b * NREL + kb_rel[fid]];
    W_tilde[fid] = wt;
    atomicAdd(&e2f_sm[b * E + e2f[fid]], wt);
}

// ================= gfact =================
__global__ void k_gfact(const int* __restrict__ sorted, const int* __restrict__ kb_rel,
                        const int* __restrict__ e2f, const float* __restrict__ W_tilde,
                        const float* __restrict__ e2f_sm,
                        int* __restrict__ es_rel_s, float* __restrict__ g_s) {
    int j = blockIdx.x * 256 + threadIdx.x;
    if (j >= NF) return;
    int fid = sorted[j];
    int b = fid / FC;
    int es = e2f[fid], rel = kb_rel[fid];
    es_rel_s[j] = es | (rel << 16);
    g_s[j] = W_tilde[fid] / fmaxf(e2f_sm[b * E + es], VERY_SMALLF);
}

// ================= gather =================
__global__ __launch_bounds__(256) void k_gather(const int* __restrict__ es_rel_s,
                                                const float* __restrict__ g_s,
                                                const int* __restrict__ off,
                                                const float* __restrict__ self_proj_l,
                                                const float* __restrict__ head,
                                                const float* __restrict__ pr,
                                                float* __restrict__ u, float* __restrict__ pr_acc) {
    int bid = blockIdx.x;
    int job = (bid & 7) * 500 + (bid >> 3);
    int wave = threadIdx.x >> 6, lane = threadIdx.x & 63;
    int ri = job * 4 + wave;
    int b = ri / E, bE = b * E;
    int s = off[ri], e = off[ri + 1];
    float a0 = 0.f, a1 = 0.f, ns = 0.f;
    const float* hb = head + (size_t)bE * D;
    const float* prb = pr + bE;
    for (int cs = s; cs < e; cs += 64) {
        int cnt = e - cs; if (cnt > 64) cnt = 64;
        int erl = 0; float njl = 0.f;
        if (lane < cnt) {
            erl = es_rel_s[cs + lane];
            njl = g_s[cs + lane] * prb[erl & 0xffff];
        }
        for (int j = 0; j < cnt; ++j) {
            int er = __shfl(erl, j);
            float nj = __shfl(njl, j);
            int es = er & 0xffff, rel = er >> 16;
            const float* sp = self_proj_l + rel * D;
            const float* hr = hb + (size_t)es * D;
            a0 += nj * fmaxf(0.f, sp[lane] + hr[lane]);
            if (lane < 36) a1 += nj * fmaxf(0.f, sp[lane + 64] + hr[lane + 64]);
            ns += nj;
        }
    }
    u[(size_t)ri * D + lane] = a0;
    if (lane < 36) u[(size_t)ri * D + 64 + lane] = a1;
    if (lane == 0) pr_acc[ri] = ns;
}

// ================= tailent (16-row tiles, 1000 blocks) =================
struct TailP {
    const float *u, *cnt_f, *tailWt_l, *tail_b_l;
    const float *cur, *lee_self_in, *q2e_l, *e2eWt_l, *e2e_b_l;
    const float *pr_acc_c; float *pr; float *nxt;
    const float *headWt_n, *head_b_n, *selfWt_n, *self_b_n;
    float *head, *lee_self_out;
    int last; const int *local_entity; const float *score_W, *score_b; float *out;
};

__global__ __launch_bounds__(256) void k_tailent(TailP p) {
    __shared__ float As_[16 * 104];
    __shared__ float Bs_[100 * 100];
    __shared__ float Fs_[16 * 104];
    int tid = threadIdx.x, base = blockIdx.x * 16;
    int cg_ = tid & 31, rg = tid >> 5, cgc = cg_ < 25 ? cg_ : 24;
    for (int i = tid; i < 400; i += 256) {
        int r = i / 25, c = i - r * 25;
        *(float4*)&As_[r * 104 + c * 4] = *(const float4*)&p.u[(size_t)(base + r) * 100 + c * 4];
    }
    stage_B100(p.tailWt_l, 100, 0, 0, Bs_);
    __syncthreads();
    float accF[2][4] = {{0.f}};
    tile8(As_, Bs_, rg, cgc, accF);
    __syncthreads();
    if (cg_ < 25) {
        float4 tbv = *(const float4*)&p.tail_b_l[cg_ * 4];
#pragma unroll
        for (int i = 0; i < 2; ++i) {
            int r = base + rg * 2 + i;
            float cf = p.cnt_f[r];
            float4 ls = *(const float4*)&p.lee_self_in[(size_t)r * 100 + cg_ * 4];
            float4 o;
            o.x = 3.f * fmaxf(0.f, ls.x + accF[i][0] + cf * tbv.x);
            o.y = 3.f * fmaxf(0.f, ls.y + accF[i][1] + cf * tbv.y);
            o.z = 3.f * fmaxf(0.f, ls.z + accF[i][2] + cf * tbv.z);
            o.w = 3.f * fmaxf(0.f, ls.w + accF[i][3] + cf * tbv.w);
            *(float4*)&Fs_[(rg * 2 + i) * 104 + cg_ * 4] = o;
        }
    }
    if (tid < 16) {
        int r = base + tid;
        p.pr[r] = 0.8f * p.pr_acc_c[r] + 0.2f * p.pr[r];
    }
    float acc[2][4] = {{0.f}};
    __syncthreads();
    for (int i = tid; i < 400; i += 256) {
        int r = i / 25, c = i - r * 25;
        *(float4*)&As_[r * 104 + c * 4] = *(const float4*)&p.cur[(size_t)(base + r) * 100 + c * 4];
    }
    stage_B100(p.e2eWt_l, 100, 0, 0, Bs_);
    __syncthreads();
    tile8(As_, Bs_, rg, cgc, acc);
    __syncthreads();
    for (int i = tid; i < 400; i += 256) {
        int r = i / 25, c = i - r * 25;
        int bb = (base + r) / E;
        *(float4*)&As_[r * 104 + c * 4] = *(const float4*)&p.q2e_l[bb * 100 + c * 4];
    }
    stage_B100(p.e2eWt_l, 100, 0, 100, Bs_);
    __syncthreads();
    tile8(As_, Bs_, rg, cgc, acc);
    __syncthreads();
    stage_B100(p.e2eWt_l, 100, 0, 200, Bs_);
    __syncthreads();
    tile8(Fs_, Bs_, rg, cgc, acc);
    __syncthreads();
    if (cg_ < 25) {
        float4 ebv = *(const float4*)&p.e2e_b_l[cg_ * 4];
#pragma unroll
        for (int i = 0; i < 2; ++i) {
            int r = base + rg * 2 + i;
            float4 o;
            o.x = fmaxf(acc[i][0] + ebv.x, 0.f); o.y = fmaxf(acc[i][1] + ebv.y, 0.f);
            o.z = fmaxf(acc[i][2] + ebv.z, 0.f); o.w = fmaxf(acc[i][3] + ebv.w, 0.f);
            *(float4*)&p.nxt[(size_t)r * 100 + cg_ * 4] = o;
            *(float4*)&As_[(rg * 2 + i) * 104 + cg_ * 4] = o;
        }
    }
    if (!p.last) {
        stage_B100(p.headWt_n, 100, 0, 0, Bs_);
        __syncthreads();
        float a2[2][4] = {{0.f}};
        tile8(As_, Bs_, rg, cgc, a2);
        if (cg_ < 25) {
            float4 bb = *(const float4*)&p.head_b_n[cg_ * 4];
#pragma unroll
            for (int i = 0; i < 2; ++i) {
                int r = base + rg * 2 + i;
                float4 o;
                o.x = a2[i][0] + bb.x; o.y = a2[i][1] + bb.y;
                o.z = a2[i][2] + bb.z; o.w = a2[i][3] + bb.w;
                *(float4*)&p.head[(size_t)r * 100 + cg_ * 4] = o;
            }
        }
        __syncthreads();
        stage_B100(p.selfWt_n, 100, 0, 0, Bs_);
        __syncthreads();
        float a3[2][4] = {{0.f}};
        tile8(As_, Bs_, rg, cgc, a3);
        if (cg_ < 25) {
            float4 bb = *(const float4*)&p.self_b_n[cg_ * 4];
#pragma unroll
            for (int i = 0; i < 2; ++i) {
                int r = base + rg * 2 + i;
                float4 o;
                o.x = a3[i][0] + bb.x; o.y = a3[i][1] + bb.y;
                o.z = a3[i][2] + bb.z; o.w = a3[i][3] + bb.w;
                *(float4*)&p.lee_self_out[(size_t)r * 100 + cg_ * 4] = o;
            }
        }
    } else {
        __syncthreads();
        if (tid < 16) {
            int r = base + tid;
            if (p.local_entity[r] == NE) { p.out[r] = 0.f; }
            else {
                float a = p.score_b[0];
                for (int k = 0; k < D; ++k) a += As_[tid * 104 + k] * p.score_W[k];
                p.out[r] = 1.f / (1.f + expf(-a));
            }
        }
    }
}

extern "C" void kernel_launch(void* const* d_in, const int* in_sizes, int n_in,
                              void* d_out, int out_size, void* d_ws, size_t ws_size,
                              hipStream_t stream) {
    const int*   local_entity = (const int*)d_in[0];
    const float* q2e_adj      = (const float*)d_in[1];
    const int*   kb_rel       = (const int*)d_in[2];
    const int*   qtext        = (const int*)d_in[3];
    const int*   e2f          = (const int*)d_in[4];
    const int*   f2e          = (const int*)d_in[5];
    const float* word_emb     = (const float*)d_in[7];
    const float* entity_emb   = (const float*)d_in[8];
    const float* rel_emb      = (const float*)d_in[9];
    const float* ent_W        = (const float*)d_in[10];
    const float* ent_b        = (const float*)d_in[11];
    const float* rel_W        = (const float*)d_in[12];
    const float* rel_b        = (const float*)d_in[13];
    const float* lstm_Wih     = (const float*)d_in[14];
    const float* lstm_Whh     = (const float*)d_in[15];
    const float* lstm_bih     = (const float*)d_in[16];
    const float* lstm_bhh     = (const float*)d_in[17];
    const float* q2e_W        = (const float*)d_in[18];
    const float* q2e_b        = (const float*)d_in[19];
    const float* head_W       = (const float*)d_in[20];
    const float* head_b       = (const float*)d_in[21];
    const float* tail_W       = (const float*)d_in[22];
    const float* tail_b       = (const float*)d_in[23];
    const float* self_W       = (const float*)d_in[24];
    const float* self_b       = (const float*)d_in[25];
    const float* e2e_W        = (const float*)d_in[26];
    const float* e2e_b        = (const float*)d_in[27];
    const float* score_W      = (const float*)d_in[28];
    const float* score_b      = (const float*)d_in[29];

    float* ws = (float*)d_ws;
    float* rel_proj  = ws;
    float* self_proj = rel_proj  + NREL * D;
    float* xW        = self_proj + 3 * NREL * D;
    float* q2e_vec   = xW        + B * Q * G4;
    float* Wt_rel    = q2e_vec   + 3 * B * D;
    float* W_tilde   = Wt_rel    + B * NREL;
    float* e2f_sm    = W_tilde   + NF;
    float* leeA      = e2f_sm    + NR_;
    float* leeB      = leeA      + NR_ * D;
    float* head      = leeB      + NR_ * D;
    float* lee_self  = head      + NR_ * D;
    float* u_buf     = lee_self  + NR_ * D;
    float* pr        = u_buf     + NR_ * D;
    float* pr_acc    = pr        + NR_;
    float* cnt_f     = pr_acc    + NR_;
    float* g_s       = cnt_f     + NR_;
    float* entWt     = g_s       + NF;
    float* relWt     = entWt     + WD * D;
    float* WihT      = relWt     + 2 * WD * D;
    float* WhhT      = WihT      + WD * G4;
    float* headWt    = WhhT      + D * G4;
    float* selfWt    = headWt    + 3 * D * D;
    float* tailWt    = selfWt    + 3 * D * D;
    float* e2eWt     = tailWt    + 3 * D * D;
    float* bihh      = e2eWt     + 9 * D * D;
    int*   present   = (int*)(bihh + G4);
    int*   cnt       = present   + B * NREL;
    int*   cursor    = cnt       + NRP;
    int*   off       = cursor    + NR_;
    int*   sorted    = off       + NR_ + 1;
    int*   es_rel_s  = sorted    + NF;

    hipMemsetAsync(present, 0, (size_t)(B * NREL + NRP) * sizeof(int), stream);

    P0 p0;
    p0.ent_W = ent_W; p0.rel_W = rel_W; p0.Wih = lstm_Wih; p0.Whh = lstm_Whh;
    p0.head_W = head_W; p0.self_W = self_W; p0.tail_W = tail_W; p0.e2e_W = e2e_W;
    p0.bih = lstm_bih; p0.bhh = lstm_bhh; p0.q2e_adj = q2e_adj;
    p0.entWt = entWt; p0.relWt = relWt; p0.WihT = WihT; p0.WhhT = WhhT;
    p0.headWt = headWt; p0.selfWt = selfWt; p0.tailWt = tailWt; p0.e2eWt = e2eWt;
    p0.bihh = bihh; p0.pr = pr; p0.e2f_sm = e2f_sm;
    p0.f2e = f2e; p0.kb_rel = kb_rel; p0.cnt = cnt; p0.present = present;
    k_prep0<<<971, 256, 0, stream>>>(p0);

    F1P f1;
    f1.cnt = cnt; f1.off = off; f1.cursor = cursor; f1.cnt_f = cnt_f;
    f1.word_emb = word_emb; f1.qtext = qtext; f1.WihT = WihT; f1.bihh = bihh; f1.xW = xW;
    f1.rel_emb = rel_emb; f1.relWt = relWt; f1.rel_b = rel_b; f1.rel_proj = rel_proj;
    f1.entity_emb = entity_emb; f1.local_entity = local_entity;
    f1.entWt = entWt; f1.ent_b = ent_b;
    f1.headWt0 = headWt; f1.head_b0 = head_b; f1.selfWt0 = selfWt; f1.self_b0 = self_b;
    f1.lee = leeA; f1.head = head; f1.lee_self = lee_self;
    k_front1<<<31 + 1000, 256, 0, stream>>>(f1);

    F2P f2;
    f2.xW = xW; f2.WhhT = WhhT; f2.q2e_W = q2e_W; f2.q2e_b = q2e_b; f2.q2e_vec = q2e_vec;
    f2.qtext = qtext; f2.present = present;
    f2.rel_proj = rel_proj; f2.Wt_rel = Wt_rel;
    f2.selfWt = selfWt; f2.self_b = self_b; f2.self_proj = self_proj;
    k_front2<<<38, 512, 0, stream>>>(f2);

    k_scef<<<375, 256, 0, stream>>>(f2e, e2f, kb_rel, Wt_rel, cursor, sorted, W_tilde, e2f_sm);
    k_gfact<<<375, 256, 0, stream>>>(sorted, kb_rel, e2f, W_tilde, e2f_sm, es_rel_s, g_s);

    float* cur = leeA; float* nxt = leeB;
    for (int l = 0; l < 3; ++l) {
        k_gather<<<4000, 256, 0, stream>>>(es_rel_s, g_s, off, self_proj + (size_t)l * NREL * D,
                                           head, pr, u_buf, pr_acc);
        TailP tp;
        tp.u = u_buf; tp.cnt_f = cnt_f;
        tp.tailWt_l = tailWt + l * 10000; tp.tail_b_l = tail_b + l * 100;
        tp.cur = cur; tp.lee_self_in = lee_self; tp.q2e_l = q2e_vec + l * B * D;
        tp.e2eWt_l = e2eWt + l * 30000; tp.e2e_b_l = e2e_b + l * 100;
        tp.pr_acc_c = pr_acc; tp.pr = pr; tp.nxt = nxt;
        int ln = (l < 2) ? l + 1 : l;
        tp.headWt_n = headWt + ln * 10000; tp.head_b_n = head_b + ln * 100;
        tp.selfWt_n = selfWt + ln * 10000; tp.self_b_n = self_b + ln * 100;
        tp.head = head; tp.lee_self_out = lee_self;
        tp.last = (l == 2); tp.local_entity = local_entity;
        tp.score_W = score_W; tp.score_b = score_b; tp.out = (float*)d_out;
        k_tailent<<<1000, 256, 0, stream>>>(tp);
        float* t = cur; cur = nxt; nxt = t;
    }
}

// Round 14
// 299.577 us; speedup vs baseline: 1.2197x; 1.2197x over previous
//
#include <hip/hip_runtime.h>
#include <math.h>

#define VERY_NEG  -100000000000.0f
#define VERY_SMALLF 1e-10f

constexpr int B  = 8;
constexpr int E  = 2000;
constexpr int FC = 12000;
constexpr int Q  = 20;
constexpr int WD = 300;
constexpr int D  = 100;
constexpr int NW = 40000;
constexpr int NE = 100000;
constexpr int G4 = 4 * D;   // 400
constexpr int NREL = 301;
constexpr int NF = B * FC;  // 96000
constexpr int NR_ = B * E;  // 16000 rows
constexpr int NRP = 16384;

__device__ __forceinline__ float sigmoidf_(float x) { return 1.0f / (1.0f + expf(-x)); }

// ================= GEMM micro-kernels =================
// tile16: 4 rows x 4 cols per thread (32-row tiles, 256 thr)
__device__ __forceinline__ void tile16(const float* __restrict__ As_, const float* __restrict__ Bs_,
                                       int rg, int cgc, float acc[4][4]) {
#pragma unroll 5
    for (int k4 = 0; k4 < 25; ++k4) {
        float a_[4][4], b_[4][4];
#pragma unroll
        for (int i = 0; i < 4; ++i) {
            float4 v = *(const float4*)&As_[(rg * 4 + i) * 104 + k4 * 4];
            a_[i][0] = v.x; a_[i][1] = v.y; a_[i][2] = v.z; a_[i][3] = v.w;
        }
#pragma unroll
        for (int kk = 0; kk < 4; ++kk) {
            float4 v = *(const float4*)&Bs_[(k4 * 4 + kk) * 100 + cgc * 4];
            b_[kk][0] = v.x; b_[kk][1] = v.y; b_[kk][2] = v.z; b_[kk][3] = v.w;
        }
#pragma unroll
        for (int kk = 0; kk < 4; ++kk)
#pragma unroll
            for (int i = 0; i < 4; ++i)
#pragma unroll
                for (int j = 0; j < 4; ++j)
                    acc[i][j] += a_[i][kk] * b_[kk][j];
    }
}

// tile8: 2 rows x 4 cols per thread (32-row tiles, 512 thr: rg in [0,16))
__device__ __forceinline__ void tile8(const float* __restrict__ As_, const float* __restrict__ Bs_,
                                      int rg, int cgc, float acc[2][4]) {
#pragma unroll 5
    for (int k4 = 0; k4 < 25; ++k4) {
        float a_[2][4], b_[4][4];
#pragma unroll
        for (int i = 0; i < 2; ++i) {
            float4 v = *(const float4*)&As_[(rg * 2 + i) * 104 + k4 * 4];
            a_[i][0] = v.x; a_[i][1] = v.y; a_[i][2] = v.z; a_[i][3] = v.w;
        }
#pragma unroll
        for (int kk = 0; kk < 4; ++kk) {
            float4 v = *(const float4*)&Bs_[(k4 * 4 + kk) * 100 + cgc * 4];
            b_[kk][0] = v.x; b_[kk][1] = v.y; b_[kk][2] = v.z; b_[kk][3] = v.w;
        }
#pragma unroll
        for (int kk = 0; kk < 4; ++kk)
#pragma unroll
            for (int i = 0; i < 2; ++i)
#pragma unroll
                for (int j = 0; j < 4; ++j)
                    acc[i][j] += a_[i][kk] * b_[kk][j];
    }
}

__device__ __forceinline__ void stage_B100_512(const float* __restrict__ Wt, int ldW, int col0, int k0,
                                               float* __restrict__ Bs_) {
    for (int i = threadIdx.x; i < 2500; i += 512) {
        int k = i / 25, d2 = i - k * 25;
        *(float4*)&Bs_[k * 100 + d2 * 4] = *(const float4*)&Wt[(size_t)(k0 + k) * ldW + col0 + d2 * 4];
    }
}

// 32-row tile for 512-thread blocks (compute on tid<256 via tile16)
__device__ void gemm_tile_512(const float* __restrict__ A, int K,
                              const int* __restrict__ rix, int nrows,
                              const float* __restrict__ Wt, int ldW, int col0,
                              const float* __restrict__ bias,
                              float* __restrict__ C,
                              int base, float* As_, float* Bs_) {
    int tid = threadIdx.x;
    int cg_ = tid & 31, rg = (tid >> 5) & 7, cgc = cg_ < 25 ? cg_ : 24;
    bool on = tid < 256;
    float acc[4][4] = {{0.f}};
    for (int k0 = 0; k0 < K; k0 += 100) {
        __syncthreads();
        for (int i = tid; i < 800; i += 512) {
            int r = i / 25, c = i - r * 25;
            int rr = base + r; if (rr >= nrows) rr = nrows - 1;
            int gr = rix ? rix[rr] : rr;
            *(float4*)&As_[r * 104 + c * 4] = *(const float4*)&A[(size_t)gr * K + k0 + c * 4];
        }
        stage_B100_512(Wt, ldW, col0, k0, Bs_);
        __syncthreads();
        if (on) tile16(As_, Bs_, rg, cgc, acc);
    }
    if (on && cg_ < 25) {
        float4 bb = *(const float4*)&bias[col0 + cg_ * 4];
#pragma unroll
        for (int i = 0; i < 4; ++i) {
            int r = base + rg * 4 + i;
            if (r < nrows) {
                float4 o;
                o.x = acc[i][0] + bb.x; o.y = acc[i][1] + bb.y;
                o.z = acc[i][2] + bb.z; o.w = acc[i][3] + bb.w;
                *(float4*)&C[(size_t)r * ldW + col0 + cg_ * 4] = o;
            }
        }
    }
}

// ================= prep0: transposes + fills + hist (256 thr) =================
struct P0 {
    const float *ent_W, *rel_W, *Wih, *Whh, *head_W, *self_W, *tail_W, *e2e_W, *bih, *bhh, *q2e_adj;
    float *entWt, *relWt, *WihT, *WhhT, *headWt, *selfWt, *tailWt, *e2eWt, *bihh, *pr, *e2f_sm;
    const int *f2e, *kb_rel; int *cnt, *present;
};

__device__ void tr_tile(const float* __restrict__ in, float* __restrict__ out, int M, int K,
                        int kx, int my, float tb[32][33]) {
    int x = threadIdx.x & 31, y = threadIdx.x >> 5;
    int k0 = kx * 32, m0 = my * 32;
    for (int yy = y; yy < 32; yy += 8) {
        int m = m0 + yy, k = k0 + x;
        if (m < M && k < K) tb[yy][x] = in[(size_t)m * K + k];
    }
    __syncthreads();
    for (int yy = y; yy < 32; yy += 8) {
        int k = k0 + yy, m = m0 + x;
        if (m < M && k < K) out[(size_t)k * M + m] = tb[x][yy];
    }
}

__global__ __launch_bounds__(256) void k_prep0(P0 p) {
    __shared__ float tb[32][33];
    int j = blockIdx.x, tid = threadIdx.x;
    if (j < 40)       { tr_tile(p.ent_W, p.entWt, 100, 300, j % 10, j / 10, tb); }
    else if (j < 116) { j -= 40;  tr_tile(p.rel_W, p.relWt, 100, 600, j % 19, j / 19, tb); }
    else if (j < 246) { j -= 116; tr_tile(p.Wih, p.WihT, 400, 300, j % 10, j / 10, tb); }
    else if (j < 298) { j -= 246; tr_tile(p.Whh, p.WhhT, 400, 100, j % 4, j / 4, tb); }
    else if (j < 346) { j -= 298; int z = j / 16, t = j % 16; tr_tile(p.head_W + z * 10000, p.headWt + z * 10000, 100, 100, t % 4, t / 4, tb); }
    else if (j < 394) { j -= 346; int z = j / 16, t = j % 16; tr_tile(p.self_W + z * 10000, p.selfWt + z * 10000, 100, 100, t % 4, t / 4, tb); }
    else if (j < 442) { j -= 394; int z = j / 16, t = j % 16; tr_tile(p.tail_W + z * 10000, p.tailWt + z * 10000, 100, 100, t % 4, t / 4, tb); }
    else if (j < 562) { j -= 442; int z = j / 40, t = j % 40; tr_tile(p.e2e_W + z * 30000, p.e2eWt + z * 30000, 100, 300, t % 10, t / 10, tb); }
    else if (j < 564) { int idx = (j - 562) * 256 + tid; if (idx < G4) p.bihh[idx] = p.bih[idx] + p.bhh[idx]; }
    else if (j < 580) { int idx = (j - 564) * 256 + tid; if (idx < 4000) ((float4*)p.pr)[idx] = ((const float4*)p.q2e_adj)[idx]; }
    else if (j < 596) { int idx = (j - 580) * 256 + tid; if (idx < 4000) ((float4*)p.e2f_sm)[idx] = make_float4(0.f, 0.f, 0.f, 0.f); }
    else {
        int fid = (j - 596) * 256 + tid;   // [0, 96000) exact
        int b = fid / FC;
        atomicAdd(&p.cnt[b * E + p.f2e[fid]], 1);
        p.present[b * NREL + p.kb_rel[fid]] = 1;
    }
}

// ================= front1 (512 thr): scan + xW + rel_proj + lee_dual =================
struct F1P {
    const int *cnt; int *off, *cursor; float *cnt_f;
    const float *word_emb; const int *qtext; const float *WihT, *bihh; float *xW;
    const float *rel_emb, *relWt, *rel_b; float *rel_proj;
    const float *entity_emb; const int *local_entity;
    const float *entWt, *ent_b, *headWt0, *head_b0, *selfWt0, *self_b0;
    float *lee, *head, *lee_self;
};

// 512-thread-safe scan (threads >=256 only participate in barriers)
__device__ void scan_block(const int* __restrict__ cnt, int* __restrict__ off,
                           int* __restrict__ cursor, float* __restrict__ cnt_f, int* part) {
    int t = threadIdx.x;
    int s = 0;
    if (t < 256) {
        const int4* c4 = (const int4*)(cnt + t * 64);
#pragma unroll 4
        for (int i = 0; i < 16; ++i) { int4 v = c4[i]; s += v.x + v.y + v.z + v.w; }
    }
    part[t] = (t < 256) ? s : 0;
    __syncthreads();
    for (int d = 1; d < 256; d <<= 1) {
        int add = (t >= d) ? part[t - d] : 0;
        __syncthreads();
        part[t] += add;
        __syncthreads();
    }
    if (t < 256) {
        int run = part[t] - s;
        for (int i = 0; i < 64; ++i) {
            int idx = t * 64 + i;
            if (idx < NR_) {
                off[idx] = run; cursor[idx] = run; cnt_f[idx] = (float)cnt[idx];
                run += cnt[idx];
            }
        }
    }
    if (t == 255) off[NR_] = part[255];
}

__device__ void lee_dual_tile32(int base, const F1P& p, float* As_, float* Bs_) {
    int tid = threadIdx.x;                 // 512
    int cg_ = tid & 31, rg = tid >> 5;     // rg in [0,16)
    int cgc = cg_ < 25 ? cg_ : 24;
    float acc[2][4] = {{0.f}};
    for (int k0 = 0; k0 < 300; k0 += 100) {
        __syncthreads();
        for (int i = tid; i < 800; i += 512) {
            int r = i / 25, c = i - r * 25;
            int gr = p.local_entity[base + r];
            *(float4*)&As_[r * 104 + c * 4] = *(const float4*)&p.entity_emb[(size_t)gr * 300 + k0 + c * 4];
        }
        stage_B100_512(p.entWt, 100, 0, k0, Bs_);
        __syncthreads();
        tile8(As_, Bs_, rg, cgc, acc);
    }
    __syncthreads();
    if (cg_ < 25) {
        float4 bb = *(const float4*)&p.ent_b[cg_ * 4];
#pragma unroll
        for (int i = 0; i < 2; ++i) {
            int r = base + rg * 2 + i;
            float4 o;
            o.x = acc[i][0] + bb.x; o.y = acc[i][1] + bb.y;
            o.z = acc[i][2] + bb.z; o.w = acc[i][3] + bb.w;
            *(float4*)&p.lee[(size_t)r * 100 + cg_ * 4] = o;
            *(float4*)&As_[(rg * 2 + i) * 104 + cg_ * 4] = o;
        }
    }
    stage_B100_512(p.headWt0, 100, 0, 0, Bs_);
    __syncthreads();
    float acc2[2][4] = {{0.f}};
    tile8(As_, Bs_, rg, cgc, acc2);
    if (cg_ < 25) {
        float4 bb = *(const float4*)&p.head_b0[cg_ * 4];
#pragma unroll
        for (int i = 0; i < 2; ++i) {
            int r = base + rg * 2 + i;
            float4 o;
            o.x = acc2[i][0] + bb.x; o.y = acc2[i][1] + bb.y;
            o.z = acc2[i][2] + bb.z; o.w = acc2[i][3] + bb.w;
            *(float4*)&p.head[(size_t)r * 100 + cg_ * 4] = o;
        }
    }
    __syncthreads();
    stage_B100_512(p.selfWt0, 100, 0, 0, Bs_);
    __syncthreads();
    float acc3[2][4] = {{0.f}};
    tile8(As_, Bs_, rg, cgc, acc3);
    if (cg_ < 25) {
        float4 bb = *(const float4*)&p.self_b0[cg_ * 4];
#pragma unroll
        for (int i = 0; i < 2; ++i) {
            int r = base + rg * 2 + i;
            float4 o;
            o.x = acc3[i][0] + bb.x; o.y = acc3[i][1] + bb.y;
            o.z = acc3[i][2] + bb.z; o.w = acc3[i][3] + bb.w;
            *(float4*)&p.lee_self[(size_t)r * 100 + cg_ * 4] = o;
        }
    }
}

__global__ __launch_bounds__(512) void k_front1(F1P p) {
    __shared__ float smem[13328];
    int j = blockIdx.x;
    if (j == 0) {
        scan_block(p.cnt, p.off, p.cursor, p.cnt_f, (int*)smem);
    } else if (j <= 20) {
        j -= 1;
        gemm_tile_512(p.word_emb, WD, p.qtext, B * Q, p.WihT, G4, (j / 5) * 100, p.bihh,
                      p.xW, (j % 5) * 32, smem, smem + 3328);
    } else if (j <= 30) {
        j -= 21;
        gemm_tile_512(p.rel_emb, 2 * WD, nullptr, NREL, p.relWt, D, 0, p.rel_b,
                      p.rel_proj, j * 32, smem, smem + 3328);
    } else {
        lee_dual_tile32((j - 31) * 32, p, smem, smem + 3328);
    }
}

// ================= front2: LSTM+q2e+wfall fused + self_proj (512 thr) =================
struct F2P {
    const float *xW, *WhhT, *q2e_W, *q2e_b; float *q2e_vec;
    const int *qtext, *present;
    const float *rel_proj; float *Wt_rel;
    const float *selfWt, *self_b; float *self_proj;
};

__device__ void lstm_wfall_block(int b, const F2P& p, float* smem) {
    float* h    = smem;
    float* c    = smem + 128;
    float* gate = smem + 256;
    float* qh_s = smem + 704;
    float* msk  = smem + 2704;
    float* red  = smem + 2752;
    int t = threadIdx.x;         // 512 threads
    float w[100];
    if (t < G4) {
#pragma unroll
        for (int j = 0; j < 100; ++j) w[j] = p.WhhT[j * G4 + t];
    }
    if (t < D) { h[t] = 0.f; c[t] = 0.f; }
    if (t < Q) msk[t] = (p.qtext[b * Q + t] != NW) ? 1.f : 0.f;
    __syncthreads();
    for (int step = 0; step < Q; ++step) {
        if (t < G4) {
            float a0 = 0.f, a1 = 0.f, a2 = 0.f, a3 = 0.f;
#pragma unroll
            for (int k4 = 0; k4 < 25; ++k4) {
                float4 hv = *(const float4*)&h[k4 * 4];
                a0 += hv.x * w[k4 * 4 + 0];
                a1 += hv.y * w[k4 * 4 + 1];
                a2 += hv.z * w[k4 * 4 + 2];
                a3 += hv.w * w[k4 * 4 + 3];
            }
            gate[t] = p.xW[(b * Q + step) * G4 + t] + ((a0 + a1) + (a2 + a3));
        }
        __syncthreads();
        if (t < D) {
            float ig = sigmoidf_(gate[t]);
            float fg = sigmoidf_(gate[D + t]);
            float gg = tanhf(gate[2 * D + t]);
            float og = sigmoidf_(gate[3 * D + t]);
            float cn = fg * c[t] + ig * gg;
            c[t] = cn;
            float hn = og * tanhf(cn);
            h[t] = hn;
            qh_s[step * D + t] = hn;
        }
        __syncthreads();
    }
    if (t < 3 * D) {
        int l = t / D, d = t - l * D;
        float acc = p.q2e_b[l * D + d];
        const float* W = p.q2e_W + (size_t)(l * D + d) * D;
        for (int k = 0; k < D; ++k) acc += h[k] * W[k];
        p.q2e_vec[(l * B + b) * D + d] = acc;
    }
    float wf = 0.f;
    bool active = t < NREL;
    if (active) {
        const float* lfe = p.rel_proj + t * D;
        float s[Q];
#pragma unroll
        for (int q = 0; q < Q; ++q) s[q] = 0.f;
        for (int k = 0; k < D; ++k) {
            float lv = lfe[k];
#pragma unroll
            for (int q = 0; q < Q; ++q) s[q] += qh_s[q * D + k] * lv;
        }
        float m = -INFINITY;
        float sv[Q];
#pragma unroll
        for (int q = 0; q < Q; ++q) {
            s[q] *= 0.1f;
            sv[q] = s[q] + (1.f - msk[q]) * VERY_NEG;
            m = fmaxf(m, sv[q]);
        }
        float sum = 0.f;
        float ex[Q];
#pragma unroll
        for (int q = 0; q < Q; ++q) { ex[q] = expf(sv[q] - m); sum += ex[q]; }
#pragma unroll
        for (int q = 0; q < Q; ++q) wf += (ex[q] / sum) * s[q];
    }
    red[t] = (active && p.present[b * NREL + t]) ? wf : -INFINITY;
    __syncthreads();
    for (int st = 256; st > 0; st >>= 1) {
        if (t < st) red[t] = fmaxf(red[t], red[t + st]);
        __syncthreads();
    }
    if (active) p.Wt_rel[b * NREL + t] = expf(wf - red[0]);
}

__global__ __launch_bounds__(512) void k_front2(F2P p) {
    __shared__ float smem[13328];
    int j = blockIdx.x;
    if (j < 8) {
        lstm_wfall_block(j, p, smem);
    } else {
        j -= 8;
        int z = j / 10, t = j % 10;
        gemm_tile_512(p.rel_proj, D, nullptr, NREL, p.selfWt + z * 10000, D, 0, p.self_b + z * 100,
                      p.self_proj + (size_t)z * NREL * D, t * 32, smem, smem + 3328);
    }
}

// ================= sc_ef =================
__global__ void k_scef(const int* __restrict__ f2e, const int* __restrict__ e2f,
                       const int* __restrict__ kb_rel, const float* __restrict__ Wt_rel,
                       int* __restrict__ cursor, int* __restrict__ sorted,
                       float* __restrict__ W_tilde, float* __restrict__ e2f_sm) {
    int fid = blockIdx.x * 256 + threadIdx.x;
    int b = fid / FC;
    int pos = atomicAdd(&cursor[b * E + f2e[fid]], 1);
    sorted[pos] = fid;
    float wt = Wt_rel[b * NREL + kb_rel[fid]];
    W_tilde[fid] = wt;
    atomicAdd(&e2f_sm[b * E + e2f[fid]], wt);
}

// ================= gfact =================
__global__ void k_gfact(const int* __restrict__ sorted, const int* __restrict__ kb_rel,
                        const int* __restrict__ e2f, const float* __restrict__ W_tilde,
                        const float* __restrict__ e2f_sm,
                        int* __restrict__ es_rel_s, float* __restrict__ g_s) {
    int j = blockIdx.x * 256 + threadIdx.x;
    if (j >= NF) return;
    int fid = sorted[j];
    int b = fid / FC;
    int es = e2f[fid], rel = kb_rel[fid];
    es_rel_s[j] = es | (rel << 16);
    g_s[j] = W_tilde[fid] / fmaxf(e2f_sm[b * E + es], VERY_SMALLF);
}

// ================= gather =================
__global__ __launch_bounds__(256) void k_gather(const int* __restrict__ es_rel_s,
                                                const float* __restrict__ g_s,
                                                const int* __restrict__ off,
                                                const float* __restrict__ self_proj_l,
                                                const float* __restrict__ head,
                                                const float* __restrict__ pr,
                                                float* __restrict__ u, float* __restrict__ pr_acc) {
    int bid = blockIdx.x;
    int job = (bid & 7) * 500 + (bid >> 3);
    int wave = threadIdx.x >> 6, lane = threadIdx.x & 63;
    int ri = job * 4 + wave;
    int b = ri / E, bE = b * E;
    int s = off[ri], e = off[ri + 1];
    float a0 = 0.f, a1 = 0.f, ns = 0.f;
    const float* hb = head + (size_t)bE * D;
    const float* prb = pr + bE;
    for (int cs = s; cs < e; cs += 64) {
        int cnt = e - cs; if (cnt > 64) cnt = 64;
        int erl = 0; float njl = 0.f;
        if (lane < cnt) {
            erl = es_rel_s[cs + lane];
            njl = g_s[cs + lane] * prb[erl & 0xffff];
        }
        for (int j = 0; j < cnt; ++j) {
            int er = __shfl(erl, j);
            float nj = __shfl(njl, j);
            int es = er & 0xffff, rel = er >> 16;
            const float* sp = self_proj_l + rel * D;
            const float* hr = hb + (size_t)es * D;
            a0 += nj * fmaxf(0.f, sp[lane] + hr[lane]);
            if (lane < 36) a1 += nj * fmaxf(0.f, sp[lane + 64] + hr[lane + 64]);
            ns += nj;
        }
    }
    u[(size_t)ri * D + lane] = a0;
    if (lane < 36) u[(size_t)ri * D + 64 + lane] = a1;
    if (lane == 0) pr_acc[ri] = ns;
}

// ================= tailent (512 thr, 32-row tiles, 500 blocks) =================
struct TailP {
    const float *u, *cnt_f, *tailWt_l, *tail_b_l;
    const float *cur, *lee_self_in, *q2e_l, *e2eWt_l, *e2e_b_l;
    const float *pr_acc_c; float *pr; float *nxt;
    const float *headWt_n, *head_b_n, *selfWt_n, *self_b_n;
    float *head, *lee_self_out;
    int last; const int *local_entity; const float *score_W, *score_b; float *out;
};

__global__ __launch_bounds__(512) void k_tailent(TailP p) {
    __shared__ float As_[32 * 104];
    __shared__ float Bs_[100 * 100];
    __shared__ float Fs_[32 * 104];
    int tid = threadIdx.x, base = blockIdx.x * 32;
    int cg_ = tid & 31, rg = tid >> 5;   // rg in [0,16)
    int cgc = cg_ < 25 ? cg_ : 24;
    for (int i = tid; i < 800; i += 512) {
        int r = i / 25, c = i - r * 25;
        *(float4*)&As_[r * 104 + c * 4] = *(const float4*)&p.u[(size_t)(base + r) * 100 + c * 4];
    }
    stage_B100_512(p.tailWt_l, 100, 0, 0, Bs_);
    __syncthreads();
    float accF[2][4] = {{0.f}};
    tile8(As_, Bs_, rg, cgc, accF);
    __syncthreads();
    if (cg_ < 25) {
        float4 tbv = *(const float4*)&p.tail_b_l[cg_ * 4];
#pragma unroll
        for (int i = 0; i < 2; ++i) {
            int r = base + rg * 2 + i;
            float cf = p.cnt_f[r];
            float4 ls = *(const float4*)&p.lee_self_in[(size_t)r * 100 + cg_ * 4];
            float4 o;
            o.x = 3.f * fmaxf(0.f, ls.x + accF[i][0] + cf * tbv.x);
            o.y = 3.f * fmaxf(0.f, ls.y + accF[i][1] + cf * tbv.y);
            o.z = 3.f * fmaxf(0.f, ls.z + accF[i][2] + cf * tbv.z);
            o.w = 3.f * fmaxf(0.f, ls.w + accF[i][3] + cf * tbv.w);
            *(float4*)&Fs_[(rg * 2 + i) * 104 + cg_ * 4] = o;
        }
    }
    if (tid < 32) {
        int r = base + tid;
        p.pr[r] = 0.8f * p.pr_acc_c[r] + 0.2f * p.pr[r];
    }
    float acc[2][4] = {{0.f}};
    __syncthreads();
    for (int i = tid; i < 800; i += 512) {
        int r = i / 25, c = i - r * 25;
        *(float4*)&As_[r * 104 + c * 4] = *(const float4*)&p.cur[(size_t)(base + r) * 100 + c * 4];
    }
    stage_B100_512(p.e2eWt_l, 100, 0, 0, Bs_);
    __syncthreads();
    tile8(As_, Bs_, rg, cgc, acc);
    __syncthreads();
    for (int i = tid; i < 800; i += 512) {
        int r = i / 25, c = i - r * 25;
        int bb = (base + r) / E;
        *(float4*)&As_[r * 104 + c * 4] = *(const float4*)&p.q2e_l[bb * 100 + c * 4];
    }
    stage_B100_512(p.e2eWt_l, 100, 0, 100, Bs_);
    __syncthreads();
    tile8(As_, Bs_, rg, cgc, acc);
    __syncthreads();
    stage_B100_512(p.e2eWt_l, 100, 0, 200, Bs_);
    __syncthreads();
    tile8(Fs_, Bs_, rg, cgc, acc);
    __syncthreads();
    if (cg_ < 25) {
        float4 ebv = *(const float4*)&p.e2e_b_l[cg_ * 4];
#pragma unroll
        for (int i = 0; i < 2; ++i) {
            int r = base + rg * 2 + i;
            float4 o;
            o.x = fmaxf(acc[i][0] + ebv.x, 0.f); o.y = fmaxf(acc[i][1] + ebv.y, 0.f);
            o.z = fmaxf(acc[i][2] + ebv.z, 0.f); o.w = fmaxf(acc[i][3] + ebv.w, 0.f);
            *(float4*)&p.nxt[(size_t)r * 100 + cg_ * 4] = o;
            *(float4*)&As_[(rg * 2 + i) * 104 + cg_ * 4] = o;
        }
    }
    if (!p.last) {
        stage_B100_512(p.headWt_n, 100, 0, 0, Bs_);
        __syncthreads();
        float a2[2][4] = {{0.f}};
        tile8(As_, Bs_, rg, cgc, a2);
        if (cg_ < 25) {
            float4 bb = *(const float4*)&p.head_b_n[cg_ * 4];
#pragma unroll
            for (int i = 0; i < 2; ++i) {
                int r = base + rg * 2 + i;
                float4 o;
                o.x = a2[i][0] + bb.x; o.y = a2[i][1] + bb.y;
                o.z = a2[i][2] + bb.z; o.w = a2[i][3] + bb.w;
                *(float4*)&p.head[(size_t)r * 100 + cg_ * 4] = o;
            }
        }
        __syncthreads();
        stage_B100_512(p.selfWt_n, 100, 0, 0, Bs_);
        __syncthreads();
        float a3[2][4] = {{0.f}};
        tile8(As_, Bs_, rg, cgc, a3);
        if (cg_ < 25) {
            float4 bb = *(const float4*)&p.self_b_n[cg_ * 4];
#pragma unroll
            for (int i = 0; i < 2; ++i) {
                int r = base + rg * 2 + i;
                float4 o;
                o.x = a3[i][0] + bb.x; o.y = a3[i][1] + bb.y;
                o.z = a3[i][2] + bb.z; o.w = a3[i][3] + bb.w;
                *(float4*)&p.lee_self_out[(size_t)r * 100 + cg_ * 4] = o;
            }
        }
    } else {
        __syncthreads();
        if (tid < 32) {
            int r = base + tid;
            if (p.local_entity[r] == NE) { p.out[r] = 0.f; }
            else {
                float a = p.score_b[0];
                for (int k = 0; k < D; ++k) a += As_[tid * 104 + k] * p.score_W[k];
                p.out[r] = 1.f / (1.f + expf(-a));
            }
        }
    }
}

extern "C" void kernel_launch(void* const* d_in, const int* in_sizes, int n_in,
                              void* d_out, int out_size, void* d_ws, size_t ws_size,
                              hipStream_t stream) {
    const int*   local_entity = (const int*)d_in[0];
    const float* q2e_adj      = (const float*)d_in[1];
    const int*   kb_rel       = (const int*)d_in[2];
    const int*   qtext        = (const int*)d_in[3];
    const int*   e2f          = (const int*)d_in[4];
    const int*   f2e          = (const int*)d_in[5];
    const float* word_emb     = (const float*)d_in[7];
    const float* entity_emb   = (const float*)d_in[8];
    const float* rel_emb      = (const float*)d_in[9];
    const float* ent_W        = (const float*)d_in[10];
    const float* ent_b        = (const float*)d_in[11];
    const float* rel_W        = (const float*)d_in[12];
    const float* rel_b        = (const float*)d_in[13];
    const float* lstm_Wih     = (const float*)d_in[14];
    const float* lstm_Whh     = (const float*)d_in[15];
    const float* lstm_bih     = (const float*)d_in[16];
    const float* lstm_bhh     = (const float*)d_in[17];
    const float* q2e_W        = (const float*)d_in[18];
    const float* q2e_b        = (const float*)d_in[19];
    const float* head_W       = (const float*)d_in[20];
    const float* head_b       = (const float*)d_in[21];
    const float* tail_W       = (const float*)d_in[22];
    const float* tail_b       = (const float*)d_in[23];
    const float* self_W       = (const float*)d_in[24];
    const float* self_b       = (const float*)d_in[25];
    const float* e2e_W        = (const float*)d_in[26];
    const float* e2e_b        = (const float*)d_in[27];
    const float* score_W      = (const float*)d_in[28];
    const float* score_b      = (const float*)d_in[29];

    float* ws = (float*)d_ws;
    float* rel_proj  = ws;
    float* self_proj = rel_proj  + NREL * D;
    float* xW        = self_proj + 3 * NREL * D;
    float* q2e_vec   = xW        + B * Q * G4;
    float* Wt_rel    = q2e_vec   + 3 * B * D;
    float* W_tilde   = Wt_rel    + B * NREL;
    float* e2f_sm    = W_tilde   + NF;
    float* leeA      = e2f_sm    + NR_;
    float* leeB      = leeA      + NR_ * D;
    float* head      = leeB      + NR_ * D;
    float* lee_self  = head      + NR_ * D;
    float* u_buf     = lee_self  + NR_ * D;
    float* pr        = u_buf     + NR_ * D;
    float* pr_acc    = pr        + NR_;
    float* cnt_f     = pr_acc    + NR_;
    float* g_s       = cnt_f     + NR_;
    float* entWt     = g_s       + NF;
    float* relWt     = entWt     + WD * D;
    float* WihT      = relWt     + 2 * WD * D;
    float* WhhT      = WihT      + WD * G4;
    float* headWt    = WhhT      + D * G4;
    float* selfWt    = headWt    + 3 * D * D;
    float* tailWt    = selfWt    + 3 * D * D;
    float* e2eWt     = tailWt    + 3 * D * D;
    float* bihh      = e2eWt     + 9 * D * D;
    int*   present   = (int*)(bihh + G4);
    int*   cnt       = present   + B * NREL;
    int*   cursor    = cnt       + NRP;
    int*   off       = cursor    + NR_;
    int*   sorted    = off       + NR_ + 1;
    int*   es_rel_s  = sorted    + NF;

    hipMemsetAsync(present, 0, (size_t)(B * NREL + NRP) * sizeof(int), stream);

    P0 p0;
    p0.ent_W = ent_W; p0.rel_W = rel_W; p0.Wih = lstm_Wih; p0.Whh = lstm_Whh;
    p0.head_W = head_W; p0.self_W = self_W; p0.tail_W = tail_W; p0.e2e_W = e2e_W;
    p0.bih = lstm_bih; p0.bhh = lstm_bhh; p0.q2e_adj = q2e_adj;
    p0.entWt = entWt; p0.relWt = relWt; p0.WihT = WihT; p0.WhhT = WhhT;
    p0.headWt = headWt; p0.selfWt = selfWt; p0.tailWt = tailWt; p0.e2eWt = e2eWt;
    p0.bihh = bihh; p0.pr = pr; p0.e2f_sm = e2f_sm;
    p0.f2e = f2e; p0.kb_rel = kb_rel; p0.cnt = cnt; p0.present = present;
    k_prep0<<<971, 256, 0, stream>>>(p0);

    F1P f1;
    f1.cnt = cnt; f1.off = off; f1.cursor = cursor; f1.cnt_f = cnt_f;
    f1.word_emb = word_emb; f1.qtext = qtext; f1.WihT = WihT; f1.bihh = bihh; f1.xW = xW;
    f1.rel_emb = rel_emb; f1.relWt = relWt; f1.rel_b = rel_b; f1.rel_proj = rel_proj;
    f1.entity_emb = entity_emb; f1.local_entity = local_entity;
    f1.entWt = entWt; f1.ent_b = ent_b;
    f1.headWt0 = headWt; f1.head_b0 = head_b; f1.selfWt0 = selfWt; f1.self_b0 = self_b;
    f1.lee = leeA; f1.head = head; f1.lee_self = lee_self;
    k_front1<<<531, 512, 0, stream>>>(f1);

    F2P f2;
    f2.xW = xW; f2.WhhT = WhhT; f2.q2e_W = q2e_W; f2.q2e_b = q2e_b; f2.q2e_vec = q2e_vec;
    f2.qtext = qtext; f2.present = present;
    f2.rel_proj = rel_proj; f2.Wt_rel = Wt_rel;
    f2.selfWt = selfWt; f2.self_b = self_b; f2.self_proj = self_proj;
    k_front2<<<38, 512, 0, stream>>>(f2);

    k_scef<<<375, 256, 0, stream>>>(f2e, e2f, kb_rel, Wt_rel, cursor, sorted, W_tilde, e2f_sm);
    k_gfact<<<375, 256, 0, stream>>>(sorted, kb_rel, e2f, W_tilde, e2f_sm, es_rel_s, g_s);

    float* cur = leeA; float* nxt = leeB;
    for (int l = 0; l < 3; ++l) {
        k_gather<<<4000, 256, 0, stream>>>(es_rel_s, g_s, off, self_proj + (size_t)l * NREL * D,
                                           head, pr, u_buf, pr_acc);
        TailP tp;
        tp.u = u_buf; tp.cnt_f = cnt_f;
        tp.tailWt_l = tailWt + l * 10000; tp.tail_b_l = tail_b + l * 100;
        tp.cur = cur; tp.lee_self_in = lee_self; tp.q2e_l = q2e_vec + l * B * D;
        tp.e2eWt_l = e2eWt + l * 30000; tp.e2e_b_l = e2e_b + l * 100;
        tp.pr_acc_c = pr_acc; tp.pr = pr; tp.nxt = nxt;
        int ln = (l < 2) ? l + 1 : l;
        tp.headWt_n = headWt + ln * 10000; tp.head_b_n = head_b + ln * 100;
        tp.selfWt_n = selfWt + ln * 10000; tp.self_b_n = self_b + ln * 100;
        tp.head = head; tp.lee_self_out = lee_self;
        tp.last = (l == 2); tp.local_entity = local_entity;
        tp.score_W = score_W; tp.score_b = score_b; tp.out = (float*)d_out;
        k_tailent<<<500, 512, 0, stream>>>(tp);
        float* t = cur; cur = nxt; nxt = t;
    }
}